// Round 1
// baseline (267.696 us; speedup 1.0000x reference)
//
#include <hip/hip_runtime.h>

#define B_    4
#define N_    11
#define D_    589824L     // 64*96*96
#define NPAIR 66          // upper-tri incl. diagonal, 11*12/2
#define TPB   256
#define ITER  8           // floats per block = TPB*4*ITER = 8192; 589824/8192 = 72 blocks/batch

// ---------------------------------------------------------------------------
// Pass 1: pairwise reductions. energy2[p] = <q_i,q_j>, energy1[p] = sum|q_i-q_j|
// for all 66 (i<=j) pairs, accumulated per-batch via fp64 atomics.
// ---------------------------------------------------------------------------
__global__ __launch_bounds__(TPB) void reduce_kernel(const float* __restrict__ x,
                                                     double* __restrict__ e2ws,
                                                     double* __restrict__ e1ws) {
    const int b = blockIdx.y;
    const int t = threadIdx.x;
    const long base = (long)blockIdx.x * (TPB * 4 * ITER) + (long)t * 4;
    const float* xb = x + (long)b * N_ * D_;

    float acc2[NPAIR];
    float acc1[NPAIR];
#pragma unroll
    for (int p = 0; p < NPAIR; ++p) { acc2[p] = 0.f; acc1[p] = 0.f; }

#pragma unroll 1
    for (int k = 0; k < ITER; ++k) {
        const long d = base + (long)k * (TPB * 4);
        float4 v[N_];
#pragma unroll
        for (int m = 0; m < N_; ++m)
            v[m] = *reinterpret_cast<const float4*>(xb + (long)m * D_ + d);

        int p = 0;
#pragma unroll
        for (int i = 0; i < N_; ++i) {
#pragma unroll
            for (int j = i; j < N_; ++j) {
                acc2[p] += v[i].x * v[j].x + v[i].y * v[j].y +
                           v[i].z * v[j].z + v[i].w * v[j].w;
                if (i != j) {
                    acc1[p] += fabsf(v[i].x - v[j].x) + fabsf(v[i].y - v[j].y) +
                               fabsf(v[i].z - v[j].z) + fabsf(v[i].w - v[j].w);
                }
                ++p;
            }
        }
    }

    // intra-wave shuffle reduce, then cross-wave via LDS
    __shared__ float red2[TPB / 64][NPAIR];
    __shared__ float red1[TPB / 64][NPAIR];
    const int wave = t >> 6, lane = t & 63;
#pragma unroll
    for (int p = 0; p < NPAIR; ++p) {
        float s2 = acc2[p], s1 = acc1[p];
#pragma unroll
        for (int off = 32; off > 0; off >>= 1) {
            s2 += __shfl_down(s2, off, 64);
            s1 += __shfl_down(s1, off, 64);
        }
        if (lane == 0) { red2[wave][p] = s2; red1[wave][p] = s1; }
    }
    __syncthreads();
    if (t < NPAIR) {
        float s2 = 0.f, s1 = 0.f;
#pragma unroll
        for (int w = 0; w < TPB / 64; ++w) { s2 += red2[w][t]; s1 += red1[w][t]; }
        atomicAdd(&e2ws[b * NPAIR + t], (double)s2);
        atomicAdd(&e1ws[b * NPAIR + t], (double)s1);
    }
}

// ---------------------------------------------------------------------------
// Pass 2: energy = e1*e2 (symmetric); attention = softmax(-energy) per row;
// M[n,m] = gamma*attention[n,m] + (n==m).
// ---------------------------------------------------------------------------
__global__ __launch_bounds__(128) void attn_kernel(const double* __restrict__ e2ws,
                                                   const double* __restrict__ e1ws,
                                                   const float* __restrict__ gamma,
                                                   float* __restrict__ Mws) {
    const int b = blockIdx.x;
    const int t = threadIdx.x;
    __shared__ double E[N_][N_];
    if (t < NPAIR) {
        // decode upper-tri index t -> (i, j)
        int rem = t, i = 0, cnt = N_;
        while (rem >= cnt) { rem -= cnt; --cnt; ++i; }
        const int j = i + rem;
        const double e = e1ws[b * NPAIR + t] * e2ws[b * NPAIR + t];
        E[i][j] = e;
        E[j][i] = e;
    }
    __syncthreads();
    if (t < N_) {
        const int i = t;
        double mn = E[i][0];
#pragma unroll
        for (int j = 1; j < N_; ++j) mn = fmin(mn, E[i][j]);
        double ex[N_], s = 0.0;
#pragma unroll
        for (int j = 0; j < N_; ++j) { ex[j] = exp(mn - E[i][j]); s += ex[j]; }
        const float g = gamma[0];
        const double inv = 1.0 / s;
#pragma unroll
        for (int j = 0; j < N_; ++j) {
            float m = (float)(ex[j] * inv) * g + (i == j ? 1.0f : 0.0f);
            Mws[(b * N_ + i) * N_ + j] = m;
        }
    }
}

// ---------------------------------------------------------------------------
// Pass 3: out[b,n,d] = sum_m M[b][n][m] * x[b,m,d]   (gamma & +x folded into M)
// ---------------------------------------------------------------------------
__global__ __launch_bounds__(TPB) void apply_kernel(const float* __restrict__ x,
                                                    const float* __restrict__ Mws,
                                                    float* __restrict__ out) {
    const int b = blockIdx.y;
    const int t = threadIdx.x;
    __shared__ float M[N_ * N_];
    if (t < N_ * N_) M[t] = Mws[b * N_ * N_ + t];
    __syncthreads();

    const long d = (long)blockIdx.x * (TPB * 4) + (long)t * 4;
    const float* xb = x + (long)b * N_ * D_;
    float* ob = out + (long)b * N_ * D_;

    float4 v[N_];
#pragma unroll
    for (int m = 0; m < N_; ++m)
        v[m] = *reinterpret_cast<const float4*>(xb + (long)m * D_ + d);

#pragma unroll
    for (int n = 0; n < N_; ++n) {
        float4 o = make_float4(0.f, 0.f, 0.f, 0.f);
#pragma unroll
        for (int m = 0; m < N_; ++m) {
            const float w = M[n * N_ + m];
            o.x += w * v[m].x;
            o.y += w * v[m].y;
            o.z += w * v[m].z;
            o.w += w * v[m].w;
        }
        *reinterpret_cast<float4*>(ob + (long)n * D_ + d) = o;
    }
}

// ---------------------------------------------------------------------------
extern "C" void kernel_launch(void* const* d_in, const int* in_sizes, int n_in,
                              void* d_out, int out_size, void* d_ws, size_t ws_size,
                              hipStream_t stream) {
    const float* x     = (const float*)d_in[0];
    const float* gamma = (const float*)d_in[1];
    float* out         = (float*)d_out;

    double* e2ws = (double*)d_ws;
    double* e1ws = e2ws + B_ * NPAIR;
    float*  Mws  = (float*)(e1ws + B_ * NPAIR);

    // zero the fp64 accumulators (ws is poisoned to 0xAA before every launch)
    hipMemsetAsync(d_ws, 0, (size_t)(2 * B_ * NPAIR) * sizeof(double), stream);

    dim3 gridA(D_ / (TPB * 4 * ITER), B_);   // (72, 4)
    reduce_kernel<<<gridA, TPB, 0, stream>>>(x, e2ws, e1ws);

    attn_kernel<<<B_, 128, 0, stream>>>(e2ws, e1ws, gamma, Mws);

    dim3 gridC(D_ / (TPB * 4), B_);          // (576, 4)
    apply_kernel<<<gridC, TPB, 0, stream>>>(x, Mws, out);
}